// Round 3
// baseline (508.074 us; speedup 1.0000x reference)
//
#include <hip/hip_runtime.h>
#include <stdint.h>

typedef float vfloat4 __attribute__((ext_vector_type(4)));
typedef float vfloat2 __attribute__((ext_vector_type(2)));

// ---------------------------------------------------------------------------
// Kernel 1: Wf[v] = token_mask[v] * (W_cls @ W_embed)[:, v], stored interleaved
// as float2 so any v index is 8B-aligned. (reads W_embed 154 MB once)
// ---------------------------------------------------------------------------
__global__ __launch_bounds__(256) void fuse_weights_kernel(
    const float* __restrict__ Wemb,   // [H][V]
    const float* __restrict__ tmask,  // [V]
    const float* __restrict__ Wcls,   // [2][H]
    float2* __restrict__ wf2,         // [V]
    int V, int H)
{
    __shared__ float sW0[1024];
    __shared__ float sW1[1024];
    __shared__ float part[4][64][2];

    for (int i = threadIdx.x; i < H; i += blockDim.x) {
        sW0[i] = Wcls[i];
        sW1[i] = Wcls[H + i];
    }
    __syncthreads();

    const int vl = threadIdx.x & 63;
    const int hg = threadIdx.x >> 6;
    const int v  = blockIdx.x * 64 + vl;

    float a0 = 0.f, a1 = 0.f;
    if (v < V) {
        for (int h = hg; h < H; h += 4) {
            float w = Wemb[(size_t)h * (size_t)V + v];
            a0 = fmaf(w, sW0[h], a0);
            a1 = fmaf(w, sW1[h], a1);
        }
    }
    part[hg][vl][0] = a0;
    part[hg][vl][1] = a1;
    __syncthreads();

    if (hg == 0 && v < V) {
        float r0 = (part[0][vl][0] + part[1][vl][0]) + (part[2][vl][0] + part[3][vl][0]);
        float r1 = (part[0][vl][1] + part[1][vl][1]) + (part[2][vl][1] + part[3][vl][1]);
        float m = tmask[v];
        wf2[v] = make_float2(r0 * m, r1 * m);
    }
}

// ---------------------------------------------------------------------------
// Kernel 2: partial sums over a (v-chunk, token-group) tile.
// Block stages wf2[chunk] (32 KB) into LDS once, then streams the chunk's
// v-window of TG=16 tokens from HBM (nontemporal, read-once), accumulating
// per-token (s, d0, d1). Partials -> d_ws (no atomics, deterministic).
// ---------------------------------------------------------------------------
constexpr int CHUNK = 4096;
constexpr int TG    = 16;

__global__ __launch_bounds__(256) void partial_kernel(
    const float* __restrict__ emb,   // [T][V]
    const float2* __restrict__ wf2,  // [V] interleaved {w0, w1}
    float4* __restrict__ part,       // [NC][T]  {S, D0, D1, pad}
    const int V, const int T, const int NC)
{
    __shared__ float2 lw[CHUNK];
    __shared__ float red[4][TG][3];

    const int c    = blockIdx.x % NC;
    const int g    = blockIdx.x / NC;
    const int v0   = c * CHUNK;
    const int clen = min(CHUNK, V - v0);
    const int tid  = threadIdx.x;

    // stage wf2 chunk into LDS (coalesced 8B/lane)
    for (int i = tid; i < clen; i += 256) lw[i] = wf2[v0 + i];
    __syncthreads();

    const int t0 = g * TG;
    float sA[TG], dA0[TG], dA1[TG];

    #pragma unroll
    for (int tk = 0; tk < TG; ++tk) {
        const float* row = emb + (size_t)(t0 + tk) * (size_t)V + v0;
        const int mis = (int)((((uintptr_t)row) >> 2) & 3);
        int head = (4 - mis) & 3;
        if (head > clen) head = clen;

        float s = 0.f, d0 = 0.f, d1 = 0.f;

        if (tid < head) {
            float e = __builtin_nontemporal_load(row + tid);
            float2 w = lw[tid];
            s = e; d0 = e * w.x; d1 = e * w.y;
        }

        const int nb = (clen - head) >> 2;
        const int ts = head + (nb << 2);
        const int nt = clen - ts;
        if (tid < nt) {
            float e = __builtin_nontemporal_load(row + ts + tid);
            float2 w = lw[ts + tid];
            s += e; d0 = fmaf(e, w.x, d0); d1 = fmaf(e, w.y, d1);
        }

        const vfloat4* e4 = (const vfloat4*)(row + head);
        for (int j = tid; j < nb; j += 256) {
            vfloat4 ev = __builtin_nontemporal_load(e4 + j);
            const int vl = head + (j << 2);
            float2 w0 = lw[vl];
            float2 w1 = lw[vl + 1];
            float2 w2 = lw[vl + 2];
            float2 w3 = lw[vl + 3];
            s += (ev.x + ev.y) + (ev.z + ev.w);
            d0 = fmaf(ev.x, w0.x, d0);
            d0 = fmaf(ev.y, w1.x, d0);
            d0 = fmaf(ev.z, w2.x, d0);
            d0 = fmaf(ev.w, w3.x, d0);
            d1 = fmaf(ev.x, w0.y, d1);
            d1 = fmaf(ev.y, w1.y, d1);
            d1 = fmaf(ev.z, w2.y, d1);
            d1 = fmaf(ev.w, w3.y, d1);
        }
        sA[tk] = s; dA0[tk] = d0; dA1[tk] = d1;
    }

    // wave shuffle reduce + cross-wave LDS reduce, all TG tokens
    #pragma unroll
    for (int tk = 0; tk < TG; ++tk) {
        float s = sA[tk], d0 = dA0[tk], d1 = dA1[tk];
        #pragma unroll
        for (int off = 32; off > 0; off >>= 1) {
            s  += __shfl_xor(s,  off);
            d0 += __shfl_xor(d0, off);
            d1 += __shfl_xor(d1, off);
        }
        if ((tid & 63) == 0) {
            const int w = tid >> 6;
            red[w][tk][0] = s; red[w][tk][1] = d0; red[w][tk][2] = d1;
        }
    }
    __syncthreads();

    if (tid < TG) {
        float S  = (red[0][tid][0] + red[1][tid][0]) + (red[2][tid][0] + red[3][tid][0]);
        float D0 = (red[0][tid][1] + red[1][tid][1]) + (red[2][tid][1] + red[3][tid][1]);
        float D1 = (red[0][tid][2] + red[1][tid][2]) + (red[2][tid][2] + red[3][tid][2]);
        part[(size_t)c * T + (t0 + tid)] = make_float4(S, D0, D1, 0.f);
    }
}

// ---------------------------------------------------------------------------
// Kernel 3: finalize. out[t] = D/S + b. Reads NC partials per token, fixed
// summation order -> deterministic.
// ---------------------------------------------------------------------------
__global__ __launch_bounds__(256) void finalize_kernel(
    const float4* __restrict__ part, // [NC][T]
    const float* __restrict__ bcls,  // [2]
    float2* __restrict__ out,        // [T]
    const int T, const int NC)
{
    const int t = blockIdx.x * 256 + threadIdx.x;
    if (t >= T) return;
    float S = 0.f, D0 = 0.f, D1 = 0.f;
    for (int c = 0; c < NC; ++c) {
        float4 p = part[(size_t)c * T + t];
        S += p.x; D0 += p.y; D1 += p.z;
    }
    out[t] = make_float2(D0 / S + bcls[0], D1 / S + bcls[1]);
}

extern "C" void kernel_launch(void* const* d_in, const int* in_sizes, int n_in,
                              void* d_out, int out_size, void* d_ws, size_t ws_size,
                              hipStream_t stream) {
    const float* emb   = (const float*)d_in[0];   // [B,S,V] f32
    // d_in[1]: attention_masks (all-ones, unused by the math)
    const float* Wemb  = (const float*)d_in[2];   // [H,V] f32
    const float* tmask = (const float*)d_in[3];   // [V] f32
    const float* Wcls  = (const float*)d_in[4];   // [2,H] f32
    const float* bcls  = (const float*)d_in[5];   // [2] f32

    const int V = in_sizes[3];                    // 50265
    const int T = in_sizes[1];                    // B*S = 8192
    const int H = in_sizes[2] / V;                // 768
    const int NC = (V + CHUNK - 1) / CHUNK;       // 13

    // ws layout: [wf2: V float2][partials: NC*T float4]
    float2* wf2  = (float2*)d_ws;
    size_t wf2_bytes = ((size_t)V * sizeof(float2) + 255) & ~(size_t)255;
    float4* part = (float4*)((char*)d_ws + wf2_bytes);

    // Kernel 1: fused classifier-through-embedding weight (2 x V)
    const int blocks1 = (V + 63) / 64;
    fuse_weights_kernel<<<blocks1, 256, 0, stream>>>(Wemb, tmask, Wcls, wf2, V, H);

    // Kernel 2: (chunk x token-group) partial sums
    const int blocks2 = NC * (T / TG);
    partial_kernel<<<blocks2, 256, 0, stream>>>(emb, wf2, part, V, T, NC);

    // Kernel 3: finalize logits
    const int blocks3 = (T + 255) / 256;
    finalize_kernel<<<blocks3, 256, 0, stream>>>(part, bcls, (float2*)d_out, T, NC);
}

// Round 4
// 419.988 us; speedup vs baseline: 1.2097x; 1.2097x over previous
//
#include <hip/hip_runtime.h>
#include <stdint.h>

typedef float vfloat4 __attribute__((ext_vector_type(4)));

// ---------------------------------------------------------------------------
// Kernel 1: Wf[v] = token_mask[v] * (W_cls @ W_embed)[:, v], stored interleaved
// as float2 (8B-aligned for any v). Reads W_embed (154 MB) once.
// ---------------------------------------------------------------------------
__global__ __launch_bounds__(256) void fuse_weights_kernel(
    const float* __restrict__ Wemb,   // [H][V]
    const float* __restrict__ tmask,  // [V]
    const float* __restrict__ Wcls,   // [2][H]
    float2* __restrict__ wf2,         // [V]
    int V, int H)
{
    __shared__ float sW0[1024];
    __shared__ float sW1[1024];
    __shared__ float part[4][64][2];

    for (int i = threadIdx.x; i < H; i += blockDim.x) {
        sW0[i] = Wcls[i];
        sW1[i] = Wcls[H + i];
    }
    __syncthreads();

    const int vl = threadIdx.x & 63;
    const int hg = threadIdx.x >> 6;
    const int v  = blockIdx.x * 64 + vl;

    float a0 = 0.f, a1 = 0.f;
    if (v < V) {
        for (int h = hg; h < H; h += 4) {
            float w = Wemb[(size_t)h * (size_t)V + v];
            a0 = fmaf(w, sW0[h], a0);
            a1 = fmaf(w, sW1[h], a1);
        }
    }
    part[hg][vl][0] = a0;
    part[hg][vl][1] = a1;
    __syncthreads();

    if (hg == 0 && v < V) {
        float r0 = (part[0][vl][0] + part[1][vl][0]) + (part[2][vl][0] + part[3][vl][0]);
        float r1 = (part[0][vl][1] + part[1][vl][1]) + (part[2][vl][1] + part[3][vl][1]);
        float m = tmask[v];
        wf2[v] = make_float2(r0 * m, r1 * m);
    }
}

// ---------------------------------------------------------------------------
// Kernel 2: partial sums over a (v-chunk, token-group) tile.
// LDS holds the chunk's weights as TWO PLANES (lw0, lw1) so the hot loop reads
// them as aligned ds_read_b128, lane-stride 16B -> conflict-free (round-3's
// interleaved float2 layout was a 16-way bank conflict = 5.69x LDS cost).
// v-iteration is chunk-aligned; the per-token misalignment (V odd) is absorbed
// by unaligned 16B global loads of emb (__builtin_memcpy, 4B-aligned).
// ---------------------------------------------------------------------------
constexpr int CHUNK = 4096;
constexpr int TG    = 16;

__global__ __launch_bounds__(256) void partial_kernel(
    const float* __restrict__ emb,   // [T][V]
    const float2* __restrict__ wf2,  // [V] interleaved {w0, w1}
    float4* __restrict__ part,       // [NC][T]  {S, D0, D1, pad}
    const int V, const int T, const int NC)
{
    __shared__ float lw0[CHUNK];
    __shared__ float lw1[CHUNK];
    __shared__ float red[4][TG][3];

    const int c    = blockIdx.x % NC;
    const int g    = blockIdx.x / NC;
    const int v0   = c * CHUNK;
    const int clen = min(CHUNK, V - v0);
    const int tid  = threadIdx.x;

    // stage wf2 chunk into LDS planes (8B/lane global, conflict-free writes)
    for (int i = tid; i < clen; i += 256) {
        float2 w = wf2[v0 + i];
        lw0[i] = w.x;
        lw1[i] = w.y;
    }
    __syncthreads();

    const int t0 = g * TG;
    float sA[TG], dA0[TG], dA1[TG];

    if (clen == CHUNK) {
        // fast path: fully static trip counts
        #pragma unroll
        for (int tk = 0; tk < TG; ++tk) {
            const float* rp = emb + (size_t)(t0 + tk) * (size_t)V + v0;
            float s = 0.f, d0 = 0.f, d1 = 0.f;
            #pragma unroll
            for (int jj = 0; jj < CHUNK / 1024; ++jj) {
                const int v4 = (tid + jj * 256) << 2;
                vfloat4 ev;
                __builtin_memcpy(&ev, rp + v4, 16);          // unaligned ok
                const vfloat4 w0 = *(const vfloat4*)(lw0 + v4); // b128, no conflict
                const vfloat4 w1 = *(const vfloat4*)(lw1 + v4);
                s += (ev.x + ev.y) + (ev.z + ev.w);
                d0 = fmaf(ev.x, w0.x, d0);
                d0 = fmaf(ev.y, w0.y, d0);
                d0 = fmaf(ev.z, w0.z, d0);
                d0 = fmaf(ev.w, w0.w, d0);
                d1 = fmaf(ev.x, w1.x, d1);
                d1 = fmaf(ev.y, w1.y, d1);
                d1 = fmaf(ev.z, w1.z, d1);
                d1 = fmaf(ev.w, w1.w, d1);
            }
            sA[tk] = s; dA0[tk] = d0; dA1[tk] = d1;
        }
    } else {
        // tail chunk (clen = V - 12*4096 = 1113)
        const int nb4 = clen >> 2;
        const int rem = clen & 3;
        #pragma unroll
        for (int tk = 0; tk < TG; ++tk) {
            const float* rp = emb + (size_t)(t0 + tk) * (size_t)V + v0;
            float s = 0.f, d0 = 0.f, d1 = 0.f;
            for (int j = tid; j < nb4; j += 256) {
                const int v4 = j << 2;
                vfloat4 ev;
                __builtin_memcpy(&ev, rp + v4, 16);
                const vfloat4 w0 = *(const vfloat4*)(lw0 + v4);
                const vfloat4 w1 = *(const vfloat4*)(lw1 + v4);
                s += (ev.x + ev.y) + (ev.z + ev.w);
                d0 = fmaf(ev.x, w0.x, d0);
                d0 = fmaf(ev.y, w0.y, d0);
                d0 = fmaf(ev.z, w0.z, d0);
                d0 = fmaf(ev.w, w0.w, d0);
                d1 = fmaf(ev.x, w1.x, d1);
                d1 = fmaf(ev.y, w1.y, d1);
                d1 = fmaf(ev.z, w1.z, d1);
                d1 = fmaf(ev.w, w1.w, d1);
            }
            if (tid < rem) {
                const int v = (nb4 << 2) + tid;
                float e = rp[v];
                s += e;
                d0 = fmaf(e, lw0[v], d0);
                d1 = fmaf(e, lw1[v], d1);
            }
            sA[tk] = s; dA0[tk] = d0; dA1[tk] = d1;
        }
    }

    // wave shuffle reduce + cross-wave LDS reduce, all TG tokens
    #pragma unroll
    for (int tk = 0; tk < TG; ++tk) {
        float s = sA[tk], d0 = dA0[tk], d1 = dA1[tk];
        #pragma unroll
        for (int off = 32; off > 0; off >>= 1) {
            s  += __shfl_xor(s,  off);
            d0 += __shfl_xor(d0, off);
            d1 += __shfl_xor(d1, off);
        }
        if ((tid & 63) == 0) {
            const int w = tid >> 6;
            red[w][tk][0] = s; red[w][tk][1] = d0; red[w][tk][2] = d1;
        }
    }
    __syncthreads();

    if (tid < TG) {
        float S  = (red[0][tid][0] + red[1][tid][0]) + (red[2][tid][0] + red[3][tid][0]);
        float D0 = (red[0][tid][1] + red[1][tid][1]) + (red[2][tid][1] + red[3][tid][1]);
        float D1 = (red[0][tid][2] + red[1][tid][2]) + (red[2][tid][2] + red[3][tid][2]);
        part[(size_t)c * T + (t0 + tid)] = make_float4(S, D0, D1, 0.f);
    }
}

// ---------------------------------------------------------------------------
// Kernel 3: finalize. out[t] = D/S + b. Fixed summation order -> deterministic.
// ---------------------------------------------------------------------------
__global__ __launch_bounds__(256) void finalize_kernel(
    const float4* __restrict__ part, // [NC][T]
    const float* __restrict__ bcls,  // [2]
    float2* __restrict__ out,        // [T]
    const int T, const int NC)
{
    const int t = blockIdx.x * 256 + threadIdx.x;
    if (t >= T) return;
    float S = 0.f, D0 = 0.f, D1 = 0.f;
    for (int c = 0; c < NC; ++c) {
        float4 p = part[(size_t)c * T + t];
        S += p.x; D0 += p.y; D1 += p.z;
    }
    out[t] = make_float2(D0 / S + bcls[0], D1 / S + bcls[1]);
}

extern "C" void kernel_launch(void* const* d_in, const int* in_sizes, int n_in,
                              void* d_out, int out_size, void* d_ws, size_t ws_size,
                              hipStream_t stream) {
    const float* emb   = (const float*)d_in[0];   // [B,S,V] f32
    // d_in[1]: attention_masks (all-ones, unused by the math)
    const float* Wemb  = (const float*)d_in[2];   // [H,V] f32
    const float* tmask = (const float*)d_in[3];   // [V] f32
    const float* Wcls  = (const float*)d_in[4];   // [2,H] f32
    const float* bcls  = (const float*)d_in[5];   // [2] f32

    const int V = in_sizes[3];                    // 50265
    const int T = in_sizes[1];                    // B*S = 8192
    const int H = in_sizes[2] / V;                // 768
    const int NC = (V + CHUNK - 1) / CHUNK;       // 13

    // ws layout: [wf2: V float2][partials: NC*T float4]
    float2* wf2  = (float2*)d_ws;
    size_t wf2_bytes = ((size_t)V * sizeof(float2) + 255) & ~(size_t)255;
    float4* part = (float4*)((char*)d_ws + wf2_bytes);

    // Kernel 1: fused classifier-through-embedding weight (2 x V)
    const int blocks1 = (V + 63) / 64;
    fuse_weights_kernel<<<blocks1, 256, 0, stream>>>(Wemb, tmask, Wcls, wf2, V, H);

    // Kernel 2: (chunk x token-group) partial sums
    const int blocks2 = NC * (T / TG);
    partial_kernel<<<blocks2, 256, 0, stream>>>(emb, wf2, part, V, T, NC);

    // Kernel 3: finalize logits
    const int blocks3 = (T + 255) / 256;
    finalize_kernel<<<blocks3, 256, 0, stream>>>(part, bcls, (float2*)d_out, T, NC);
}

// Round 5
// 377.418 us; speedup vs baseline: 1.3462x; 1.1128x over previous
//
#include <hip/hip_runtime.h>
#include <stdint.h>

typedef float vfloat4 __attribute__((ext_vector_type(4)));

constexpr int CHUNK = 4096;
constexpr int TG    = 16;
constexpr int VT    = 2048;   // k1a v-tile width (floats); thread owns 8 v
constexpr int MAXNG = 24;     // max h-groups (HS = 32 rows each)

// ---------------------------------------------------------------------------
// Kernel 1a (streaming): partial GEMV over an (h-group, v-tile) tile.
// Reads W_embed ROW-MAJOR: each wave-instr covers 2KB contiguous (32B/lane),
// unlike the old column-panel walk (256B reads at 201KB stride = random-ish
// DRAM traffic). Partials -> d_ws [NG][2][Vp].
// ---------------------------------------------------------------------------
__global__ __launch_bounds__(256) void fuse_partial_kernel(
    const float* __restrict__ Wemb,   // [H][V] row-major
    const float* __restrict__ Wcls,   // [2][H]
    float* __restrict__ part,         // [NG][2][Vp]
    const int V, const int Vp, const int H, const int NG, const int NVT)
{
    __shared__ float sW0[1024];
    __shared__ float sW1[1024];
    for (int i = threadIdx.x; i < H; i += 256) { sW0[i] = Wcls[i]; sW1[i] = Wcls[H + i]; }
    __syncthreads();

    const int vt = blockIdx.x % NVT;   // consecutive blocks -> adjacent v-tiles
    const int g  = blockIdx.x / NVT;
    const int HS = (H + NG - 1) / NG;
    const int h0 = g * HS;
    const int h1 = min(H, h0 + HS);
    const int v  = vt * VT + (int)threadIdx.x * 8;

    float a0[8], a1[8];
    #pragma unroll
    for (int k = 0; k < 8; ++k) { a0[k] = 0.f; a1[k] = 0.f; }

    if (v + 8 <= V) {
        for (int h = h0; h < h1; ++h) {
            const float* p = Wemb + (size_t)h * (size_t)V + v;
            vfloat4 x0, x1;                       // rows misaligned (V odd) ->
            __builtin_memcpy(&x0, p,     16);     // unaligned-safe loads
            __builtin_memcpy(&x1, p + 4, 16);
            const float w0 = sW0[h], w1 = sW1[h];
            a0[0] = fmaf(w0, x0.x, a0[0]);
            a0[1] = fmaf(w0, x0.y, a0[1]);
            a0[2] = fmaf(w0, x0.z, a0[2]);
            a0[3] = fmaf(w0, x0.w, a0[3]);
            a0[4] = fmaf(w0, x1.x, a0[4]);
            a0[5] = fmaf(w0, x1.y, a0[5]);
            a0[6] = fmaf(w0, x1.z, a0[6]);
            a0[7] = fmaf(w0, x1.w, a0[7]);
            a1[0] = fmaf(w1, x0.x, a1[0]);
            a1[1] = fmaf(w1, x0.y, a1[1]);
            a1[2] = fmaf(w1, x0.z, a1[2]);
            a1[3] = fmaf(w1, x0.w, a1[3]);
            a1[4] = fmaf(w1, x1.x, a1[4]);
            a1[5] = fmaf(w1, x1.y, a1[5]);
            a1[6] = fmaf(w1, x1.z, a1[6]);
            a1[7] = fmaf(w1, x1.w, a1[7]);
        }
        float* p0 = part + (size_t)g * 2 * (size_t)Vp + v;   // 32B-aligned (v mult of 8, Vp mult of 8)
        float* p1 = p0 + Vp;
        vfloat4 s00 = {a0[0], a0[1], a0[2], a0[3]};
        vfloat4 s01 = {a0[4], a0[5], a0[6], a0[7]};
        vfloat4 s10 = {a1[0], a1[1], a1[2], a1[3]};
        vfloat4 s11 = {a1[4], a1[5], a1[6], a1[7]};
        *(vfloat4*)(p0)     = s00;
        *(vfloat4*)(p0 + 4) = s01;
        *(vfloat4*)(p1)     = s10;
        *(vfloat4*)(p1 + 4) = s11;
    } else if (v < V) {
        // tail v-tile: guarded scalars
        for (int h = h0; h < h1; ++h) {
            const float w0 = sW0[h], w1 = sW1[h];
            const float* p = Wemb + (size_t)h * (size_t)V;
            #pragma unroll
            for (int k = 0; k < 8; ++k) {
                if (v + k < V) {
                    float x = p[v + k];
                    a0[k] = fmaf(w0, x, a0[k]);
                    a1[k] = fmaf(w1, x, a1[k]);
                }
            }
        }
        float* p0 = part + (size_t)g * 2 * (size_t)Vp;
        #pragma unroll
        for (int k = 0; k < 8; ++k) {
            if (v + k < V) { p0[v + k] = a0[k]; p0[Vp + v + k] = a1[k]; }
        }
    }
}

// ---------------------------------------------------------------------------
// Kernel 1b: reduce NG partial segments, apply token_mask, emit wf2 (float2).
// ---------------------------------------------------------------------------
__global__ __launch_bounds__(256) void fuse_reduce_kernel(
    const float* __restrict__ part,   // [NG][2][Vp]
    const float* __restrict__ tmask,  // [V]
    float2* __restrict__ wf2,         // [V]
    const int V, const int Vp, const int NG)
{
    const int v = blockIdx.x * 256 + threadIdx.x;
    if (v >= V) return;
    float s0 = 0.f, s1 = 0.f;
    for (int g = 0; g < NG; ++g) {
        const float* p0 = part + (size_t)g * 2 * (size_t)Vp;
        s0 += p0[v];
        s1 += p0[Vp + v];
    }
    const float m = tmask[v];
    wf2[v] = make_float2(s0 * m, s1 * m);
}

// ---------------------------------------------------------------------------
// Kernel 1 (fallback, column version) — used only if ws_size can't hold the
// k1a partials. Identical to round 4.
// ---------------------------------------------------------------------------
__global__ __launch_bounds__(256) void fuse_weights_kernel(
    const float* __restrict__ Wemb,   // [H][V]
    const float* __restrict__ tmask,  // [V]
    const float* __restrict__ Wcls,   // [2][H]
    float2* __restrict__ wf2,         // [V]
    int V, int H)
{
    __shared__ float sW0[1024];
    __shared__ float sW1[1024];
    __shared__ float part[4][64][2];

    for (int i = threadIdx.x; i < H; i += blockDim.x) {
        sW0[i] = Wcls[i];
        sW1[i] = Wcls[H + i];
    }
    __syncthreads();

    const int vl = threadIdx.x & 63;
    const int hg = threadIdx.x >> 6;
    const int v  = blockIdx.x * 64 + vl;

    float a0 = 0.f, a1 = 0.f;
    if (v < V) {
        for (int h = hg; h < H; h += 4) {
            float w = Wemb[(size_t)h * (size_t)V + v];
            a0 = fmaf(w, sW0[h], a0);
            a1 = fmaf(w, sW1[h], a1);
        }
    }
    part[hg][vl][0] = a0;
    part[hg][vl][1] = a1;
    __syncthreads();

    if (hg == 0 && v < V) {
        float r0 = (part[0][vl][0] + part[1][vl][0]) + (part[2][vl][0] + part[3][vl][0]);
        float r1 = (part[0][vl][1] + part[1][vl][1]) + (part[2][vl][1] + part[3][vl][1]);
        float m = tmask[v];
        wf2[v] = make_float2(r0 * m, r1 * m);
    }
}

// ---------------------------------------------------------------------------
// Kernel 2: UNCHANGED from round 4 (two-plane LDS, conflict-free b128 reads).
// ---------------------------------------------------------------------------
__global__ __launch_bounds__(256) void partial_kernel(
    const float* __restrict__ emb,   // [T][V]
    const float2* __restrict__ wf2,  // [V] interleaved {w0, w1}
    float4* __restrict__ part,       // [NC][T]  {S, D0, D1, pad}
    const int V, const int T, const int NC)
{
    __shared__ float lw0[CHUNK];
    __shared__ float lw1[CHUNK];
    __shared__ float red[4][TG][3];

    const int c    = blockIdx.x % NC;
    const int g    = blockIdx.x / NC;
    const int v0   = c * CHUNK;
    const int clen = min(CHUNK, V - v0);
    const int tid  = threadIdx.x;

    for (int i = tid; i < clen; i += 256) {
        float2 w = wf2[v0 + i];
        lw0[i] = w.x;
        lw1[i] = w.y;
    }
    __syncthreads();

    const int t0 = g * TG;
    float sA[TG], dA0[TG], dA1[TG];

    if (clen == CHUNK) {
        #pragma unroll
        for (int tk = 0; tk < TG; ++tk) {
            const float* rp = emb + (size_t)(t0 + tk) * (size_t)V + v0;
            float s = 0.f, d0 = 0.f, d1 = 0.f;
            #pragma unroll
            for (int jj = 0; jj < CHUNK / 1024; ++jj) {
                const int v4 = (tid + jj * 256) << 2;
                vfloat4 ev;
                __builtin_memcpy(&ev, rp + v4, 16);
                const vfloat4 w0 = *(const vfloat4*)(lw0 + v4);
                const vfloat4 w1 = *(const vfloat4*)(lw1 + v4);
                s += (ev.x + ev.y) + (ev.z + ev.w);
                d0 = fmaf(ev.x, w0.x, d0);
                d0 = fmaf(ev.y, w0.y, d0);
                d0 = fmaf(ev.z, w0.z, d0);
                d0 = fmaf(ev.w, w0.w, d0);
                d1 = fmaf(ev.x, w1.x, d1);
                d1 = fmaf(ev.y, w1.y, d1);
                d1 = fmaf(ev.z, w1.z, d1);
                d1 = fmaf(ev.w, w1.w, d1);
            }
            sA[tk] = s; dA0[tk] = d0; dA1[tk] = d1;
        }
    } else {
        const int nb4 = clen >> 2;
        const int rem = clen & 3;
        #pragma unroll
        for (int tk = 0; tk < TG; ++tk) {
            const float* rp = emb + (size_t)(t0 + tk) * (size_t)V + v0;
            float s = 0.f, d0 = 0.f, d1 = 0.f;
            for (int j = tid; j < nb4; j += 256) {
                const int v4 = j << 2;
                vfloat4 ev;
                __builtin_memcpy(&ev, rp + v4, 16);
                const vfloat4 w0 = *(const vfloat4*)(lw0 + v4);
                const vfloat4 w1 = *(const vfloat4*)(lw1 + v4);
                s += (ev.x + ev.y) + (ev.z + ev.w);
                d0 = fmaf(ev.x, w0.x, d0);
                d0 = fmaf(ev.y, w0.y, d0);
                d0 = fmaf(ev.z, w0.z, d0);
                d0 = fmaf(ev.w, w0.w, d0);
                d1 = fmaf(ev.x, w1.x, d1);
                d1 = fmaf(ev.y, w1.y, d1);
                d1 = fmaf(ev.z, w1.z, d1);
                d1 = fmaf(ev.w, w1.w, d1);
            }
            if (tid < rem) {
                const int v = (nb4 << 2) + tid;
                float e = rp[v];
                s += e;
                d0 = fmaf(e, lw0[v], d0);
                d1 = fmaf(e, lw1[v], d1);
            }
            sA[tk] = s; dA0[tk] = d0; dA1[tk] = d1;
        }
    }

    #pragma unroll
    for (int tk = 0; tk < TG; ++tk) {
        float s = sA[tk], d0 = dA0[tk], d1 = dA1[tk];
        #pragma unroll
        for (int off = 32; off > 0; off >>= 1) {
            s  += __shfl_xor(s,  off);
            d0 += __shfl_xor(d0, off);
            d1 += __shfl_xor(d1, off);
        }
        if ((tid & 63) == 0) {
            const int w = tid >> 6;
            red[w][tk][0] = s; red[w][tk][1] = d0; red[w][tk][2] = d1;
        }
    }
    __syncthreads();

    if (tid < TG) {
        float S  = (red[0][tid][0] + red[1][tid][0]) + (red[2][tid][0] + red[3][tid][0]);
        float D0 = (red[0][tid][1] + red[1][tid][1]) + (red[2][tid][1] + red[3][tid][1]);
        float D1 = (red[0][tid][2] + red[1][tid][2]) + (red[2][tid][2] + red[3][tid][2]);
        part[(size_t)c * T + (t0 + tid)] = make_float4(S, D0, D1, 0.f);
    }
}

// ---------------------------------------------------------------------------
// Kernel 3: finalize. out[t] = D/S + b. Fixed summation order -> deterministic.
// ---------------------------------------------------------------------------
__global__ __launch_bounds__(256) void finalize_kernel(
    const float4* __restrict__ part, // [NC][T]
    const float* __restrict__ bcls,  // [2]
    float2* __restrict__ out,        // [T]
    const int T, const int NC)
{
    const int t = blockIdx.x * 256 + threadIdx.x;
    if (t >= T) return;
    float S = 0.f, D0 = 0.f, D1 = 0.f;
    for (int c = 0; c < NC; ++c) {
        float4 p = part[(size_t)c * T + t];
        S += p.x; D0 += p.y; D1 += p.z;
    }
    out[t] = make_float2(D0 / S + bcls[0], D1 / S + bcls[1]);
}

extern "C" void kernel_launch(void* const* d_in, const int* in_sizes, int n_in,
                              void* d_out, int out_size, void* d_ws, size_t ws_size,
                              hipStream_t stream) {
    const float* emb   = (const float*)d_in[0];   // [B,S,V] f32
    // d_in[1]: attention_masks (all-ones, unused by the math)
    const float* Wemb  = (const float*)d_in[2];   // [H,V] f32
    const float* tmask = (const float*)d_in[3];   // [V] f32
    const float* Wcls  = (const float*)d_in[4];   // [2,H] f32
    const float* bcls  = (const float*)d_in[5];   // [2] f32

    const int V  = in_sizes[3];                   // 50265
    const int T  = in_sizes[1];                   // B*S = 8192
    const int H  = in_sizes[2] / V;               // 768
    const int NC = (V + CHUNK - 1) / CHUNK;       // 13
    const int Vp = (V + 7) & ~7;                  // 32B-aligned plane stride

    // ws layout: [wf2: V float2][k2 partials: NC*T float4][k1 partials: NG*2*Vp f32]
    float2* wf2 = (float2*)d_ws;
    const size_t wf2_b   = (((size_t)V * 8) + 255) & ~(size_t)255;
    const size_t k2p_b   = (((size_t)NC * T * 16) + 255) & ~(size_t)255;
    float4* k2part = (float4*)((char*)d_ws + wf2_b);
    const size_t off_k1p = wf2_b + k2p_b;
    float*  k1part = (float*)((char*)d_ws + off_k1p);

    const size_t per_g = (size_t)2 * Vp * 4;
    int NG = 0;
    if (ws_size > off_k1p) NG = (int)((ws_size - off_k1p) / per_g);
    if (NG > MAXNG) NG = MAXNG;

    if (NG >= 2) {
        const int NVT = (V + VT - 1) / VT;        // 25
        fuse_partial_kernel<<<NVT * NG, 256, 0, stream>>>(Wemb, Wcls, k1part, V, Vp, H, NG, NVT);
        fuse_reduce_kernel<<<(V + 255) / 256, 256, 0, stream>>>(k1part, tmask, wf2, V, Vp, NG);
    } else {
        const int blocks1 = (V + 63) / 64;
        fuse_weights_kernel<<<blocks1, 256, 0, stream>>>(Wemb, tmask, Wcls, wf2, V, H);
    }

    // Kernel 2: (chunk x token-group) partial sums (unchanged)
    const int blocks2 = NC * (T / TG);
    partial_kernel<<<blocks2, 256, 0, stream>>>(emb, wf2, k2part, V, T, NC);

    // Kernel 3: finalize logits
    const int blocks3 = (T + 255) / 256;
    finalize_kernel<<<blocks3, 256, 0, stream>>>(k2part, bcls, (float2*)d_out, T, NC);
}